// Round 2
// baseline (1203.994 us; speedup 1.0000x reference)
//
#include <hip/hip_runtime.h>
#include <hip/hip_fp16.h>
#include <cstdint>
#include <cstddef>

#define BB  256
#define TT  2048
#define KIN 182
#define HH  64
#define G3  192       // 3*H
#define CH  16        // timesteps per chunk (MFMA M)
#define NC  (TT/CH)   // 128 chunks
#define IGS 196       // padded fp32 row stride for igb (conflict-free producer stores)
#define BSS 200       // padded fp16 row stride for Bs (16B-aligned rows)

typedef _Float16 half8 __attribute__((ext_vector_type(8)));
typedef _Float16 h2v   __attribute__((ext_vector_type(2)));
typedef float    f32x4 __attribute__((ext_vector_type(4)));
typedef float    v2f   __attribute__((ext_vector_type(2)));

// guaranteed v_dot2_f32_f16 (no mad_mix fallback)
static __device__ __forceinline__ void dot2(float& acc, uint32_t a, uint32_t b) {
    asm("v_dot2_f32_f16 %0, %1, %2, %0" : "+v"(acc) : "v"(a), "v"(b));
}

// ---------------------------------------------------------------------------
// Fused GRU: one block per batch, 2 waves.
//   wave 1 (producer): stages W_ih once into LDS (fp16, k-padded), then per
//       chunk computes IG = x@W_ih^T + bias via 72 MFMA (bias in C-init),
//       parks fp32 results in a double-buffered LDS tile (row stride 196:
//       producer stores 2-way/free, consumer reads 2-way/free).
//   wave 0 (consumer): wave-synchronous scan, NO fences: hs double-buffered
//       (read-set/write-set disjoint per step; same-wave LDS is in-order).
//       W_hh resident as fp16 half2 in 96 VGPRs, matvec = 96 v_dot2_f32_f16.
//       Gate tail uses v_rcp_f32 instead of IEEE division. IG for step t+1
//       prefetched under step t's tail.
// ---------------------------------------------------------------------------
__global__ __launch_bounds__(128, 1) void gru_fused(
        const float* __restrict__ x,
        const float* __restrict__ wih,
        const float* __restrict__ whh,
        const float* __restrict__ bias,
        const float* __restrict__ bias_n,
        const float* __restrict__ wout,
        const float* __restrict__ outb,
        float* __restrict__ out)
{
    __shared__ float igb[2][CH][IGS];                 // 25.1 KB
    __shared__ _Float16 Bs[G3][BSS];                  // 76.8 KB, W_ih fp16 padded
    __shared__ __align__(16) _Float16 hs[2][HH];      // 256 B, h double buffer

    const int tid  = threadIdx.x;
    const int lane = tid & 63;
    const int wid  = tid >> 6;
    const int b    = blockIdx.x;

    if (wid == 1) {
        // ------------------------- producer wave --------------------------
        const int col = lane & 15;    // m (timestep row) for A, n for B/D
        const int kq  = lane >> 4;    // 0..3

        // one-time: zero k-pad [182,200), then stage W_ih -> Bs as fp16
        for (int idx = lane; idx < G3 * 18; idx += 64) {
            int n = idx / 18, k = KIN + (idx - n * 18);
            Bs[n][k] = (_Float16)0.f;
        }
        for (int idx2 = lane; idx2 < G3 * KIN / 2; idx2 += 64) {
            v2f a = ((const v2f*)wih)[idx2];          // coalesced 8B loads
            int e = 2 * idx2;
            int n = e / KIN, k = e - n * KIN;         // k even, pair in-row
            h2v t; t[0] = (_Float16)a.x; t[1] = (_Float16)a.y;
            *(h2v*)&Bs[n][k] = t;
        }

        float bv[12];
#pragma unroll
        for (int nt = 0; nt < 12; ++nt) bv[nt] = bias[nt * 16 + col];

        const float* xb = x + (size_t)b * TT * KIN;

        auto produce = [&](int c, int buf) {
            const float* xr = xb + (size_t)(c * CH + col) * KIN + kq * 8;
            half8 af[6];
#pragma unroll
            for (int kf = 0; kf < 5; ++kf) {          // k <= 158: unconditional
                v2f a0 = *(const v2f*)(xr + kf * 32 + 0);
                v2f a1 = *(const v2f*)(xr + kf * 32 + 2);
                v2f a2 = *(const v2f*)(xr + kf * 32 + 4);
                v2f a3 = *(const v2f*)(xr + kf * 32 + 6);
                half8 t;
                t[0] = (_Float16)a0.x; t[1] = (_Float16)a0.y;
                t[2] = (_Float16)a1.x; t[3] = (_Float16)a1.y;
                t[4] = (_Float16)a2.x; t[5] = (_Float16)a2.y;
                t[6] = (_Float16)a3.x; t[7] = (_Float16)a3.y;
                af[kf] = t;
            }
            {                                         // kf = 5: guard k > 180
                v2f z2; z2.x = 0.f; z2.y = 0.f;
                v2f a[4];
#pragma unroll
                for (int j = 0; j < 4; ++j) {
                    int k = 160 + kq * 8 + 2 * j;
                    a[j] = (k <= 180) ? *(const v2f*)(xr + 160 + 2 * j) : z2;
                }
                half8 t;
#pragma unroll
                for (int j = 0; j < 4; ++j) {
                    t[2 * j]     = (_Float16)a[j].x;
                    t[2 * j + 1] = (_Float16)a[j].y;
                }
                af[5] = t;
            }
#pragma unroll
            for (int nt = 0; nt < 12; ++nt) {
                const _Float16* br = &Bs[nt * 16 + col][kq * 8];
                f32x4 c4 = {bv[nt], bv[nt], bv[nt], bv[nt]};
#pragma unroll
                for (int kf = 0; kf < 6; ++kf) {
                    half8 bt = *(const half8*)(br + kf * 32);
                    c4 = __builtin_amdgcn_mfma_f32_16x16x32_f16(af[kf], bt, c4, 0, 0, 0);
                }
                // D layout: row = kq*4 + r (timestep), col = nt*16 + col (gate)
                float* dst = &igb[buf][kq * 4][nt * 16 + col];
#pragma unroll
                for (int r = 0; r < 4; ++r) dst[r * IGS] = c4[r];
            }
        };

        produce(0, 0);
        __syncthreads();                              // chunk 0 ready
        for (int c = 0; c < NC; ++c) {
            if (c + 1 < NC) produce(c + 1, (c + 1) & 1);
            __syncthreads();                          // chunk c consumed / c+1 ready
        }
    } else {
        // ------------------------- consumer wave --------------------------
        const int i = lane;                           // owns h_i and gate rows i
        // W_hh rows i, 64+i, 128+i as packed fp16 pairs: 96 VGPRs
        uint32_t wr[32], wz[32], wn[32];
        {
            const v2f* pr = (const v2f*)(whh + (size_t)(0 * HH + i) * HH);
            const v2f* pz = (const v2f*)(whh + (size_t)(1 * HH + i) * HH);
            const v2f* pn = (const v2f*)(whh + (size_t)(2 * HH + i) * HH);
#pragma unroll
            for (int k = 0; k < 32; ++k) {
                v2f a = pr[k], c2 = pz[k], d2 = pn[k];
                h2v t;
                t[0] = (_Float16)a.x;  t[1] = (_Float16)a.y;
                wr[k] = __builtin_bit_cast(uint32_t, t);
                t[0] = (_Float16)c2.x; t[1] = (_Float16)c2.y;
                wz[k] = __builtin_bit_cast(uint32_t, t);
                t[0] = (_Float16)d2.x; t[1] = (_Float16)d2.y;
                wn[k] = __builtin_bit_cast(uint32_t, t);
            }
        }
        const float bn = bias_n[i];
        float h = 0.f;
        hs[0][i] = (_Float16)0.f;                     // same-wave in-order LDS

        __syncthreads();                              // chunk 0 ready

        for (int c = 0; c < NC; ++c) {
            const float* ig0 = &igb[c & 1][0][0];
            float pr_ = ig0[i], pz_ = ig0[64 + i], pn_ = ig0[128 + i];
#pragma unroll 4
            for (int lt = 0; lt < CH; ++lt) {
                const uint4* hp = (const uint4*)hs[lt & 1];
                float r0 = 0.f, r1 = 0.f, z0 = 0.f, z1 = 0.f, n0 = 0.f, n1 = 0.f;
#pragma unroll
                for (int q = 0; q < 8; ++q) {         // 8 b128 broadcast reads
                    uint4 hv = hp[q];
                    dot2(r0, wr[4 * q + 0], hv.x);
                    dot2(z0, wz[4 * q + 0], hv.x);
                    dot2(n0, wn[4 * q + 0], hv.x);
                    dot2(r1, wr[4 * q + 1], hv.y);
                    dot2(z1, wz[4 * q + 1], hv.y);
                    dot2(n1, wn[4 * q + 1], hv.y);
                    dot2(r0, wr[4 * q + 2], hv.z);
                    dot2(z0, wz[4 * q + 2], hv.z);
                    dot2(n0, wn[4 * q + 2], hv.z);
                    dot2(r1, wr[4 * q + 3], hv.w);
                    dot2(z1, wz[4 * q + 3], hv.w);
                    dot2(n1, wn[4 * q + 3], hv.w);
                }
                float cr = pr_, cz = pz_, cn = pn_;
                if (lt != CH - 1) {                   // prefetch next step's IG
                    const float* p = ig0 + (lt + 1) * IGS;
                    pr_ = p[i]; pz_ = p[64 + i]; pn_ = p[128 + i];
                }
                // gate tail: v_rcp instead of IEEE division (~1 ulp)
                float r  = __builtin_amdgcn_rcpf(1.f + __expf(-(cr + r0 + r1)));
                float z  = __builtin_amdgcn_rcpf(1.f + __expf(-(cz + z0 + z1)));
                float e  = __expf(2.f * (cn + r * ((n0 + n1) + bn)));   // tanh
                float nn = 1.f - 2.f * __builtin_amdgcn_rcpf(e + 1.f);
                h = nn + z * (h - nn);
                hs[(lt & 1) ^ 1][i] = (_Float16)h;    // disjoint from read buf
            }
            __syncthreads();                          // hand buffer to producer
        }

        // readout: sigmoid(h . w_out^T + out_bias), butterfly reduce
        float s0 = wout[i] * h, s1 = wout[HH + i] * h;
#pragma unroll
        for (int off = 32; off > 0; off >>= 1) {
            s0 += __shfl_down(s0, off);
            s1 += __shfl_down(s1, off);
        }
        if (i == 0) {
            out[2 * b]     = __builtin_amdgcn_rcpf(1.f + __expf(-(s0 + outb[0])));
            out[2 * b + 1] = __builtin_amdgcn_rcpf(1.f + __expf(-(s1 + outb[1])));
        }
    }
}

extern "C" void kernel_launch(void* const* d_in, const int* in_sizes, int n_in,
                              void* d_out, int out_size, void* d_ws, size_t ws_size,
                              hipStream_t stream) {
    const float* x     = (const float*)d_in[0];
    const float* wih   = (const float*)d_in[1];
    const float* whh   = (const float*)d_in[2];
    const float* bias  = (const float*)d_in[3];
    const float* biasn = (const float*)d_in[4];
    const float* wout  = (const float*)d_in[5];
    const float* outb  = (const float*)d_in[6];
    float* out = (float*)d_out;
    (void)d_ws; (void)ws_size;

    gru_fused<<<BB, 128, 0, stream>>>(x, wih, whh, bias, biasn, wout, outb, out);
}

// Round 3
// 1015.997 us; speedup vs baseline: 1.1850x; 1.1850x over previous
//
#include <hip/hip_runtime.h>
#include <hip/hip_fp16.h>
#include <cstdint>
#include <cstddef>

#define BB  256
#define TT  2048
#define KIN 182
#define HH  64
#define G3  192       // 3*H
#define CH  16        // timesteps per chunk (MFMA M)
#define NC  (TT/CH)   // 128 chunks
#define IGS 196       // padded fp32 row stride: 196*4 % 128B -> producer stores 2-way (free)

typedef _Float16 half8 __attribute__((ext_vector_type(8)));
typedef _Float16 h2v   __attribute__((ext_vector_type(2)));
typedef float    f32x4 __attribute__((ext_vector_type(4)));
typedef float    v2f   __attribute__((ext_vector_type(2)));

static __device__ __forceinline__ float dot2(h2v a, h2v b, float c) {
#if __has_builtin(__builtin_amdgcn_fdot2)
    return __builtin_amdgcn_fdot2(a, b, c, false);   // builtin: compiler schedules
#else
    return c + (float)a[0] * (float)b[0] + (float)a[1] * (float)b[1];
#endif
}

// ---------------------------------------------------------------------------
// Fused GRU: one block per batch, 2 waves. (round-1 structure + isolated wins)
//   wave 1 (producer): IG chunk c+1 = x@W_ih^T + bias via 72 MFMA, A and B
//       fragments loaded straight from global (W_ih is L2-resident; keeps the
//       LDS pipe free for the consumer). fp32 park in igb, row stride 196
//       (conflict-free stores). Bias folded into MFMA C-init.
//   wave 0 (consumer): wave-synchronous scan, single hs buffer + wave_barrier
//       (proven schedule). W_hh resident as fp16 half2 in 96 VGPRs, matvec =
//       96 v_dot2_f32_f16 via builtin. Gate tail uses v_rcp_f32 (~1 ulp).
//       IG for step t+1 prefetched before the barrier, consumed next tail.
// ---------------------------------------------------------------------------
__global__ __launch_bounds__(128, 1) void gru_fused(
        const float* __restrict__ x,
        const float* __restrict__ wih,
        const float* __restrict__ whh,
        const float* __restrict__ bias,
        const float* __restrict__ bias_n,
        const float* __restrict__ wout,
        const float* __restrict__ outb,
        float* __restrict__ out)
{
    __shared__ float igb[2][CH][IGS];                 // 25.1 KB
    __shared__ __align__(16) _Float16 hs[HH];         // h broadcast

    const int tid  = threadIdx.x;
    const int lane = tid & 63;
    const int wid  = tid >> 6;
    const int b    = blockIdx.x;

    if (wid == 1) {
        // ------------------------- producer wave --------------------------
        const int col = lane & 15;    // m (timestep row) for A, n for B/D
        const int kq  = lane >> 4;    // 0..3
        float bv[12];
#pragma unroll
        for (int nt = 0; nt < 12; ++nt) bv[nt] = bias[nt * 16 + col];

        const float* xb = x + (size_t)b * TT * KIN;

        auto produce = [&](int c, int buf) {
            const float* xr = xb + (size_t)(c * CH + col) * KIN + kq * 8;
            half8 af[6];
#pragma unroll
            for (int kf = 0; kf < 5; ++kf) {          // k <= 158: unconditional
                v2f a0 = *(const v2f*)(xr + kf * 32 + 0);
                v2f a1 = *(const v2f*)(xr + kf * 32 + 2);
                v2f a2 = *(const v2f*)(xr + kf * 32 + 4);
                v2f a3 = *(const v2f*)(xr + kf * 32 + 6);
                half8 t;
                t[0] = (_Float16)a0.x; t[1] = (_Float16)a0.y;
                t[2] = (_Float16)a1.x; t[3] = (_Float16)a1.y;
                t[4] = (_Float16)a2.x; t[5] = (_Float16)a2.y;
                t[6] = (_Float16)a3.x; t[7] = (_Float16)a3.y;
                af[kf] = t;
            }
            {                                         // kf = 5: guard k > 180
                v2f z2; z2.x = 0.f; z2.y = 0.f;
                half8 t;
#pragma unroll
                for (int j = 0; j < 4; ++j) {
                    int k = 160 + kq * 8 + 2 * j;
                    v2f a = (k <= 180) ? *(const v2f*)(xr + 160 + 2 * j) : z2;
                    t[2 * j]     = (_Float16)a.x;
                    t[2 * j + 1] = (_Float16)a.y;
                }
                af[5] = t;
            }
#pragma unroll
            for (int nt = 0; nt < 12; ++nt) {
                const float* wrow = wih + (size_t)(nt * 16 + col) * KIN + kq * 8;
                f32x4 c4 = {bv[nt], bv[nt], bv[nt], bv[nt]};
#pragma unroll
                for (int kf = 0; kf < 5; ++kf) {      // unconditional B loads (L2)
                    v2f b0 = *(const v2f*)(wrow + kf * 32 + 0);
                    v2f b1 = *(const v2f*)(wrow + kf * 32 + 2);
                    v2f b2 = *(const v2f*)(wrow + kf * 32 + 4);
                    v2f b3 = *(const v2f*)(wrow + kf * 32 + 6);
                    half8 bt;
                    bt[0] = (_Float16)b0.x; bt[1] = (_Float16)b0.y;
                    bt[2] = (_Float16)b1.x; bt[3] = (_Float16)b1.y;
                    bt[4] = (_Float16)b2.x; bt[5] = (_Float16)b2.y;
                    bt[6] = (_Float16)b3.x; bt[7] = (_Float16)b3.y;
                    c4 = __builtin_amdgcn_mfma_f32_16x16x32_f16(af[kf], bt, c4, 0, 0, 0);
                }
                {                                     // kf = 5: guarded
                    v2f z2; z2.x = 0.f; z2.y = 0.f;
                    half8 bt;
#pragma unroll
                    for (int j = 0; j < 4; ++j) {
                        int k = 160 + kq * 8 + 2 * j;
                        v2f a = (k <= 180) ? *(const v2f*)(wrow + 160 + 2 * j) : z2;
                        bt[2 * j]     = (_Float16)a.x;
                        bt[2 * j + 1] = (_Float16)a.y;
                    }
                    c4 = __builtin_amdgcn_mfma_f32_16x16x32_f16(af[5], bt, c4, 0, 0, 0);
                }
                // D layout: row = kq*4 + r (timestep), col = nt*16 + col (gate)
                float* dst = &igb[buf][kq * 4][nt * 16 + col];
#pragma unroll
                for (int r = 0; r < 4; ++r) dst[r * IGS] = c4[r];
            }
        };

        produce(0, 0);
        __syncthreads();                              // chunk 0 ready
        for (int c = 0; c < NC; ++c) {
            if (c + 1 < NC) produce(c + 1, (c + 1) & 1);
            __syncthreads();                          // chunk c consumed / c+1 ready
        }
    } else {
        // ------------------------- consumer wave --------------------------
        const int i = lane;                           // owns h_i and gate rows i
        // W_hh rows i, 64+i, 128+i as fp16 half2: 96 VGPRs
        h2v wr[32], wz[32], wn[32];
        {
            const v2f* pr = (const v2f*)(whh + (size_t)(0 * HH + i) * HH);
            const v2f* pz = (const v2f*)(whh + (size_t)(1 * HH + i) * HH);
            const v2f* pn = (const v2f*)(whh + (size_t)(2 * HH + i) * HH);
#pragma unroll
            for (int k = 0; k < 32; ++k) {
                v2f a = pr[k], c2 = pz[k], d2 = pn[k];
                h2v t;
                t[0] = (_Float16)a.x;  t[1] = (_Float16)a.y;  wr[k] = t;
                t[0] = (_Float16)c2.x; t[1] = (_Float16)c2.y; wz[k] = t;
                t[0] = (_Float16)d2.x; t[1] = (_Float16)d2.y; wn[k] = t;
            }
        }
        const float bn = bias_n[i];
        float h = 0.f;
        hs[i] = (_Float16)0.f;                        // same-wave in-order LDS

        __syncthreads();                              // chunk 0 ready

        for (int c = 0; c < NC; ++c) {
            const float* ig0 = &igb[c & 1][0][0];
            // chunk-boundary IG load (exposed once per 16 steps)
            float pr_ = ig0[i], pz_ = ig0[64 + i], pn_ = ig0[128 + i];
#pragma unroll 4
            for (int lt = 0; lt < CH; ++lt) {
                const half8* hp = (const half8*)hs;
                float r0 = 0.f, r1 = 0.f, z0 = 0.f, z1 = 0.f, n0 = 0.f, n1 = 0.f;
#pragma unroll
                for (int q = 0; q < 8; ++q) {         // 8 b128 broadcast reads
                    half8 hv = hp[q];
                    h2v h0 = __builtin_shufflevector(hv, hv, 0, 1);
                    h2v h1 = __builtin_shufflevector(hv, hv, 2, 3);
                    h2v h2_ = __builtin_shufflevector(hv, hv, 4, 5);
                    h2v h3 = __builtin_shufflevector(hv, hv, 6, 7);
                    r0 = dot2(wr[4 * q + 0], h0, r0);
                    z0 = dot2(wz[4 * q + 0], h0, z0);
                    n0 = dot2(wn[4 * q + 0], h0, n0);
                    r1 = dot2(wr[4 * q + 1], h1, r1);
                    z1 = dot2(wz[4 * q + 1], h1, z1);
                    n1 = dot2(wn[4 * q + 1], h1, n1);
                    r0 = dot2(wr[4 * q + 2], h2_, r0);
                    z0 = dot2(wz[4 * q + 2], h2_, z0);
                    n0 = dot2(wn[4 * q + 2], h2_, n0);
                    r1 = dot2(wr[4 * q + 3], h3, r1);
                    z1 = dot2(wz[4 * q + 3], h3, z1);
                    n1 = dot2(wn[4 * q + 3], h3, n1);
                }
                float cr = pr_, cz = pz_, cn = pn_;
                if (lt != CH - 1) {                   // prefetch next step's IG
                    const float* p = ig0 + (lt + 1) * IGS;   // issued pre-barrier,
                    pr_ = p[i]; pz_ = p[64 + i]; pn_ = p[128 + i]; // used next tail
                }
                // gate tail: v_rcp_f32 instead of IEEE division (~1 ulp)
                float r  = __builtin_amdgcn_rcpf(1.f + __expf(-(cr + r0 + r1)));
                float z  = __builtin_amdgcn_rcpf(1.f + __expf(-(cz + z0 + z1)));
                float e  = __expf(2.f * (cn + r * ((n0 + n1) + bn)));   // tanh
                float nn = 1.f - 2.f * __builtin_amdgcn_rcpf(e + 1.f);
                h = nn + z * (h - nn);
                __builtin_amdgcn_wave_barrier();      // all hs reads issued before write
                hs[i] = (_Float16)h;
                __builtin_amdgcn_wave_barrier();      // write ordered before next reads
            }
            __syncthreads();                          // hand buffer to producer
        }

        // readout: sigmoid(h . w_out^T + out_bias), butterfly reduce
        float s0 = wout[i] * h, s1 = wout[HH + i] * h;
#pragma unroll
        for (int off = 32; off > 0; off >>= 1) {
            s0 += __shfl_down(s0, off);
            s1 += __shfl_down(s1, off);
        }
        if (i == 0) {
            out[2 * b]     = __builtin_amdgcn_rcpf(1.f + __expf(-(s0 + outb[0])));
            out[2 * b + 1] = __builtin_amdgcn_rcpf(1.f + __expf(-(s1 + outb[1])));
        }
    }
}

extern "C" void kernel_launch(void* const* d_in, const int* in_sizes, int n_in,
                              void* d_out, int out_size, void* d_ws, size_t ws_size,
                              hipStream_t stream) {
    const float* x     = (const float*)d_in[0];
    const float* wih   = (const float*)d_in[1];
    const float* whh   = (const float*)d_in[2];
    const float* bias  = (const float*)d_in[3];
    const float* biasn = (const float*)d_in[4];
    const float* wout  = (const float*)d_in[5];
    const float* outb  = (const float*)d_in[6];
    float* out = (float*)d_out;
    (void)d_ws; (void)ws_size;

    gru_fused<<<BB, 128, 0, stream>>>(x, wih, whh, bias, biasn, wout, outb, out);
}

// Round 4
// 951.122 us; speedup vs baseline: 1.2659x; 1.0682x over previous
//
#include <hip/hip_runtime.h>
#include <hip/hip_fp16.h>
#include <cstdint>
#include <cstddef>

#define BB  256
#define TT  2048
#define KIN 182
#define HH  64
#define G3  192       // 3*H
#define CH  16        // timesteps per chunk (MFMA M)
#define NC  (TT/CH)   // 128 chunks
#define IGS 196       // padded fp32 row stride: producer stores 2-way (free)

#define NFRAG (12*6*64)              // nt * kf * lane
#define WS_NEEDED ((size_t)NFRAG*16) // 73728 B of fp16 B-fragments

typedef _Float16 half8 __attribute__((ext_vector_type(8)));
typedef _Float16 h2v   __attribute__((ext_vector_type(2)));
typedef float    f32x4 __attribute__((ext_vector_type(4)));
typedef float    v2f   __attribute__((ext_vector_type(2)));

static __device__ __forceinline__ float dot2(h2v a, h2v b, float c) {
#if __has_builtin(__builtin_amdgcn_fdot2)
    return __builtin_amdgcn_fdot2(a, b, c, false);   // builtin: compiler schedules
#else
    return c + (float)a[0] * (float)b[0] + (float)a[1] * (float)b[1];
#endif
}

// ---------------------------------------------------------------------------
// One-time pre-pack: W_ih -> fp16 MFMA B-fragments in d_ws.
// Fragment (nt, kf, lane=(kq,col)) holds B[k=kf*32+kq*8+j][n=nt*16+col],
// k >= 182 zero-padded. Same RNE fp16 rounding as before -> bit-identical IG.
// ---------------------------------------------------------------------------
__global__ void pack_wih(const float* __restrict__ wih, _Float16* __restrict__ wsB) {
    int idx = blockIdx.x * 256 + threadIdx.x;
    if (idx >= NFRAG) return;
    int lane = idx & 63;
    int kf   = (idx >> 6) % 6;
    int nt   = idx / (6 * 64);
    int col  = lane & 15, kq = lane >> 4;
    int n = nt * 16 + col;
    half8 t;
#pragma unroll
    for (int j = 0; j < 8; ++j) {
        int k = kf * 32 + kq * 8 + j;
        t[j] = (k < KIN) ? (_Float16)wih[n * KIN + k] : (_Float16)0.f;
    }
    *((half8*)wsB + idx) = t;
}

// ---------------------------------------------------------------------------
// Fused GRU: one block per batch, 2 waves.
//   wave 1 (producer): IG chunk c+1 = x@W_ih^T + bias via 72 MFMA. B-frags
//       loaded PRE-PACKED fp16 from d_ws (72 coalesced dwordx4 per chunk,
//       zero cvt/pack VALU — keeps producer far below the consumer so the
//       per-chunk barrier never binds). A-frags fp32->fp16 from global x.
//       fp32 park in igb, row stride 196 (conflict-free stores).
//   wave 0 (consumer): wave-synchronous scan, single hs buffer + wave_barrier.
//       W_hh resident fp16 half2 in 96 VGPRs, 96 v_dot2_f32_f16 per step.
//       16-step loop FULLY unrolled (immediate ds offsets, no branch).
//       Gate tail uses v_rcp_f32; IG for step t+1 prefetched under the tail.
// ---------------------------------------------------------------------------
__global__ __launch_bounds__(128, 1) void gru_fused(
        const float* __restrict__ x,
        const _Float16* __restrict__ wsB,
        const float* __restrict__ whh,
        const float* __restrict__ bias,
        const float* __restrict__ bias_n,
        const float* __restrict__ wout,
        const float* __restrict__ outb,
        float* __restrict__ out)
{
    __shared__ float igb[2][CH][IGS];                 // 25.1 KB
    __shared__ __align__(16) _Float16 hs[HH];         // h broadcast

    const int tid  = threadIdx.x;
    const int lane = tid & 63;
    const int wid  = tid >> 6;
    const int b    = blockIdx.x;

    if (wid == 1) {
        // ------------------------- producer wave --------------------------
        const int col = lane & 15;    // m (timestep row) for A, n for B/D
        const int kq  = lane >> 4;    // 0..3
        float bv[12];
#pragma unroll
        for (int nt = 0; nt < 12; ++nt) bv[nt] = bias[nt * 16 + col];

        const float* xb    = x + (size_t)b * TT * KIN;
        const half8* bfrag = (const half8*)wsB + lane;   // + (nt*6+kf)*64

        auto produce = [&](int c, int buf) {
            const float* xr = xb + (size_t)(c * CH + col) * KIN + kq * 8;
            half8 af[6];
#pragma unroll
            for (int kf = 0; kf < 5; ++kf) {          // k <= 158: unconditional
                v2f a0 = *(const v2f*)(xr + kf * 32 + 0);
                v2f a1 = *(const v2f*)(xr + kf * 32 + 2);
                v2f a2 = *(const v2f*)(xr + kf * 32 + 4);
                v2f a3 = *(const v2f*)(xr + kf * 32 + 6);
                half8 t;
                t[0] = (_Float16)a0.x; t[1] = (_Float16)a0.y;
                t[2] = (_Float16)a1.x; t[3] = (_Float16)a1.y;
                t[4] = (_Float16)a2.x; t[5] = (_Float16)a2.y;
                t[6] = (_Float16)a3.x; t[7] = (_Float16)a3.y;
                af[kf] = t;
            }
            {                                         // kf = 5: guard k > 180
                v2f z2; z2.x = 0.f; z2.y = 0.f;
                half8 t;
#pragma unroll
                for (int j = 0; j < 4; ++j) {
                    int k = 160 + kq * 8 + 2 * j;
                    v2f a = (k <= 180) ? *(const v2f*)(xr + 160 + 2 * j) : z2;
                    t[2 * j]     = (_Float16)a.x;
                    t[2 * j + 1] = (_Float16)a.y;
                }
                af[5] = t;
            }
#pragma unroll
            for (int nt = 0; nt < 12; ++nt) {
                const half8* bp = bfrag + (size_t)nt * 6 * 64;
                half8 b0 = bp[0 * 64], b1 = bp[1 * 64], b2 = bp[2 * 64];
                half8 b3 = bp[3 * 64], b4 = bp[4 * 64], b5 = bp[5 * 64];
                f32x4 c4 = {bv[nt], bv[nt], bv[nt], bv[nt]};
                c4 = __builtin_amdgcn_mfma_f32_16x16x32_f16(af[0], b0, c4, 0, 0, 0);
                c4 = __builtin_amdgcn_mfma_f32_16x16x32_f16(af[1], b1, c4, 0, 0, 0);
                c4 = __builtin_amdgcn_mfma_f32_16x16x32_f16(af[2], b2, c4, 0, 0, 0);
                c4 = __builtin_amdgcn_mfma_f32_16x16x32_f16(af[3], b3, c4, 0, 0, 0);
                c4 = __builtin_amdgcn_mfma_f32_16x16x32_f16(af[4], b4, c4, 0, 0, 0);
                c4 = __builtin_amdgcn_mfma_f32_16x16x32_f16(af[5], b5, c4, 0, 0, 0);
                // D layout: row = kq*4 + r (timestep), col = nt*16 + col (gate)
                float* dst = &igb[buf][kq * 4][nt * 16 + col];
#pragma unroll
                for (int r = 0; r < 4; ++r) dst[r * IGS] = c4[r];
            }
        };

        produce(0, 0);
        __syncthreads();                              // chunk 0 ready
        for (int c = 0; c < NC; ++c) {
            if (c + 1 < NC) produce(c + 1, (c + 1) & 1);
            __syncthreads();                          // chunk c consumed / c+1 ready
        }
    } else {
        // ------------------------- consumer wave --------------------------
        const int i = lane;                           // owns h_i and gate rows i
        // W_hh rows i, 64+i, 128+i as fp16 half2: 96 VGPRs
        h2v wr[32], wz[32], wn[32];
        {
            const v2f* pr = (const v2f*)(whh + (size_t)(0 * HH + i) * HH);
            const v2f* pz = (const v2f*)(whh + (size_t)(1 * HH + i) * HH);
            const v2f* pn = (const v2f*)(whh + (size_t)(2 * HH + i) * HH);
#pragma unroll
            for (int k = 0; k < 32; ++k) {
                v2f a = pr[k], c2 = pz[k], d2 = pn[k];
                h2v t;
                t[0] = (_Float16)a.x;  t[1] = (_Float16)a.y;  wr[k] = t;
                t[0] = (_Float16)c2.x; t[1] = (_Float16)c2.y; wz[k] = t;
                t[0] = (_Float16)d2.x; t[1] = (_Float16)d2.y; wn[k] = t;
            }
        }
        const float bn = bias_n[i];
        float h = 0.f;
        hs[i] = (_Float16)0.f;                        // same-wave in-order LDS

        __syncthreads();                              // chunk 0 ready

        for (int c = 0; c < NC; ++c) {
            const float* ig0 = &igb[c & 1][0][0];
            // chunk-boundary IG load (hidden under step 0's dots)
            float pr_ = ig0[i], pz_ = ig0[64 + i], pn_ = ig0[128 + i];
#pragma unroll                                        // FULL unroll: static offsets
            for (int lt = 0; lt < CH; ++lt) {
                const half8* hp = (const half8*)hs;
                float r0 = 0.f, r1 = 0.f, z0 = 0.f, z1 = 0.f, n0 = 0.f, n1 = 0.f;
#pragma unroll
                for (int q = 0; q < 8; ++q) {         // 8 b128 broadcast reads
                    half8 hv = hp[q];
                    h2v h0 = __builtin_shufflevector(hv, hv, 0, 1);
                    h2v h1 = __builtin_shufflevector(hv, hv, 2, 3);
                    h2v h2_ = __builtin_shufflevector(hv, hv, 4, 5);
                    h2v h3 = __builtin_shufflevector(hv, hv, 6, 7);
                    r0 = dot2(wr[4 * q + 0], h0, r0);
                    z0 = dot2(wz[4 * q + 0], h0, z0);
                    n0 = dot2(wn[4 * q + 0], h0, n0);
                    r1 = dot2(wr[4 * q + 1], h1, r1);
                    z1 = dot2(wz[4 * q + 1], h1, z1);
                    n1 = dot2(wn[4 * q + 1], h1, n1);
                    r0 = dot2(wr[4 * q + 2], h2_, r0);
                    z0 = dot2(wz[4 * q + 2], h2_, z0);
                    n0 = dot2(wn[4 * q + 2], h2_, n0);
                    r1 = dot2(wr[4 * q + 3], h3, r1);
                    z1 = dot2(wz[4 * q + 3], h3, z1);
                    n1 = dot2(wn[4 * q + 3], h3, n1);
                }
                float cr = pr_, cz = pz_, cn = pn_;
                if (lt != CH - 1) {                   // folds at compile time
                    const float* p = ig0 + (lt + 1) * IGS;
                    pr_ = p[i]; pz_ = p[64 + i]; pn_ = p[128 + i];
                }
                // gate tail: v_rcp_f32 instead of IEEE division (~1 ulp)
                float r  = __builtin_amdgcn_rcpf(1.f + __expf(-(cr + r0 + r1)));
                float z  = __builtin_amdgcn_rcpf(1.f + __expf(-(cz + z0 + z1)));
                float e  = __expf(2.f * (cn + r * ((n0 + n1) + bn)));   // tanh
                float nn = 1.f - 2.f * __builtin_amdgcn_rcpf(e + 1.f);
                h = nn + z * (h - nn);
                __builtin_amdgcn_wave_barrier();      // all hs reads issued before write
                hs[i] = (_Float16)h;
                __builtin_amdgcn_wave_barrier();      // write ordered before next reads
            }
            __syncthreads();                          // hand buffer to producer
        }

        // readout: sigmoid(h . w_out^T + out_bias), butterfly reduce
        float s0 = wout[i] * h, s1 = wout[HH + i] * h;
#pragma unroll
        for (int off = 32; off > 0; off >>= 1) {
            s0 += __shfl_down(s0, off);
            s1 += __shfl_down(s1, off);
        }
        if (i == 0) {
            out[2 * b]     = __builtin_amdgcn_rcpf(1.f + __expf(-(s0 + outb[0])));
            out[2 * b + 1] = __builtin_amdgcn_rcpf(1.f + __expf(-(s1 + outb[1])));
        }
    }
}

extern "C" void kernel_launch(void* const* d_in, const int* in_sizes, int n_in,
                              void* d_out, int out_size, void* d_ws, size_t ws_size,
                              hipStream_t stream) {
    const float* x     = (const float*)d_in[0];
    const float* wih   = (const float*)d_in[1];
    const float* whh   = (const float*)d_in[2];
    const float* bias  = (const float*)d_in[3];
    const float* biasn = (const float*)d_in[4];
    const float* wout  = (const float*)d_in[5];
    const float* outb  = (const float*)d_in[6];
    float* out = (float*)d_out;

    if (ws_size < WS_NEEDED) {
        hipMemsetAsync(d_out, 0xFF, (size_t)out_size * sizeof(float), stream);
        return;
    }
    _Float16* wsB = (_Float16*)d_ws;

    pack_wih<<<(NFRAG + 255) / 256, 256, 0, stream>>>(wih, wsB);
    gru_fused<<<BB, 128, 0, stream>>>(x, wsB, whh, bias, biasn, wout, outb, out);
}